// Round 1
// baseline (1233.877 us; speedup 1.0000x reference)
//
#include <hip/hip_runtime.h>
#include <math.h>

#define DIM 10
#define WIDTH 80
#define LEN_THETA 971   // 10 + 10*80 + 80 + 80 + 1

__device__ __forceinline__ float wave_reduce_sum64(float v) {
    #pragma unroll
    for (int off = 32; off > 0; off >>= 1)
        v += __shfl_xor(v, off, 64);
    return v;
}

__global__ __launch_bounds__(256) void pinn_eval_kernel(
    const float* __restrict__ theta,
    const float* __restrict__ x,
    float* __restrict__ out,
    int npts)
{
    const int lane = threadIdx.x & 63;
    int wave = blockIdx.x * (blockDim.x >> 6) + (threadIdx.x >> 6);
    if (wave >= npts) return;
    // point index is uniform across the wave; tell the compiler so the
    // broadcast loads (beta, x, d) can scalarize.
    const int p = __builtin_amdgcn_readfirstlane(wave);

    const float* __restrict__ th = theta + (size_t)p * LEN_THETA;
    const float* __restrict__ xp = x + (size_t)p * DIM;

    const float* __restrict__ A = th + DIM;                 // [DIM][WIDTH]
    const float* __restrict__ B = th + DIM + DIM * WIDTH;   // [WIDTH]
    const float* __restrict__ C = B + WIDTH;                // [WIDTH]

    // u0[d] = sin(pi * (x_d - beta_d)) — redundant per lane, cheap.
    float u0[DIM];
    #pragma unroll
    for (int d = 0; d < DIM; ++d) {
        u0[d] = __sinf(3.14159265358979f * (xp[d] - th[d]));
    }

    // Width w1 = lane (all 64 lanes), w2 = lane + 64 (lanes 0..15).
    float acc1 = 0.f;
    #pragma unroll
    for (int d = 0; d < DIM; ++d) {
        acc1 += u0[d] * A[d * WIDTH + lane];
    }
    acc1 -= B[lane];
    // tanh(x) = 1 - 2/(exp(2x)+1)
    float e1 = __expf(2.f * acc1);
    float h1 = 1.f - 2.f / (e1 + 1.f);
    float part = h1 * C[lane];

    if (lane < (WIDTH - 64)) {
        const int w2 = 64 + lane;
        float acc2 = 0.f;
        #pragma unroll
        for (int d = 0; d < DIM; ++d) {
            acc2 += u0[d] * A[d * WIDTH + w2];
        }
        acc2 -= B[w2];
        float e2 = __expf(2.f * acc2);
        float h2 = 1.f - 2.f / (e2 + 1.f);
        part += h2 * C[w2];
    }

    float tot = wave_reduce_sum64(part);
    if (lane == 0) {
        float dsc = th[DIM + DIM * WIDTH + 2 * WIDTH];  // theta[..., 970]
        out[p] = tot - dsc;
    }
}

extern "C" void kernel_launch(void* const* d_in, const int* in_sizes, int n_in,
                              void* d_out, int out_size, void* d_ws, size_t ws_size,
                              hipStream_t stream) {
    const float* theta = (const float*)d_in[0];
    const float* x     = (const float*)d_in[1];
    float* out = (float*)d_out;

    const int npts = out_size;                 // 256*1024 = 262144
    const int waves_per_block = 4;             // 256 threads = 4 waves
    const int blocks = (npts + waves_per_block - 1) / waves_per_block;
    pinn_eval_kernel<<<blocks, 256, 0, stream>>>(theta, x, out, npts);
}